// Round 2
// baseline (341.737 us; speedup 1.0000x reference)
//
#include <hip/hip_runtime.h>

// 2-layer GRU, B=131072 seqs, T=24, H=8, fused single kernel.
// One thread per sequence. Layer-1 input gates precomputed per vocab (27x24)
// into LDS. Weights stream through scalar cache (uniform addresses -> s_load).

__device__ __forceinline__ float fsig(float x) {
  float e = __builtin_amdgcn_exp2f(-1.44269504089f * x);
  return __builtin_amdgcn_rcpf(1.0f + e);
}
__device__ __forceinline__ float ftanh_(float x) {
  float e = __builtin_amdgcn_exp2f(2.88539008178f * x);
  return 1.0f - 2.0f * __builtin_amdgcn_rcpf(1.0f + e);
}

__global__ __launch_bounds__(256, 2) void gru2_kernel(
    const int* __restrict__ inputs,
    const float* __restrict__ emb,
    const float* __restrict__ w_ih1, const float* __restrict__ w_hh1,
    const float* __restrict__ b_ih1, const float* __restrict__ b_hh1,
    const float* __restrict__ w_ih2, const float* __restrict__ w_hh2,
    const float* __restrict__ b_ih2, const float* __restrict__ b_hh2,
    float* __restrict__ out)
{
  // stride-25 padding: bank = (25*tok + g) % 32 -> distinct tokens hit
  // distinct banks (25 coprime 32, 27 < 32) -> conflict-free gi reads.
  __shared__ float G1[27 * 25];
  __shared__ int   TK[256 * 25];

  // --- precompute layer-1 input gates for all 27 vocab entries ---
  for (int idx = threadIdx.x; idx < 27 * 24; idx += 256) {
    const int v = idx / 24, g = idx % 24;
    float a = b_ih1[g];
    #pragma unroll
    for (int j = 0; j < 8; ++j) a = fmaf(w_ih1[g * 8 + j], emb[v * 8 + j], a);
    G1[v * 25 + g] = a;
  }

  // --- stage this block's 256x24 tokens, coalesced ---
  const long base = (long)blockIdx.x * (256 * 24);
  #pragma unroll
  for (int k = 0; k < 24; ++k) {
    const int i = threadIdx.x + k * 256;
    TK[(i / 24) * 25 + (i % 24)] = inputs[base + i];
  }
  __syncthreads();

  float h1[8], h2[8];
  #pragma unroll
  for (int u = 0; u < 8; ++u) { h1[u] = 0.f; h2[u] = 0.f; }

  const int trow = threadIdx.x * 25;

  for (int t = 0; t < 24; ++t) {
    const int tok = TK[trow + t];
    const float* gi1 = &G1[tok * 25];

    // ---- layer 1 cell: gh = W_hh1 @ h1 + b_hh1 ----
    float gh[24];
    #pragma unroll
    for (int g = 0; g < 24; ++g) {
      float a = b_hh1[g];
      #pragma unroll
      for (int j = 0; j < 8; ++j) a = fmaf(w_hh1[g * 8 + j], h1[j], a);
      gh[g] = a;
    }
    #pragma unroll
    for (int u = 0; u < 8; ++u) {
      const float r = fsig(gi1[u] + gh[u]);
      const float z = fsig(gi1[u + 8] + gh[u + 8]);
      const float n = ftanh_(gi1[u + 16] + r * gh[u + 16]);
      h1[u] = n + z * (h1[u] - n);   // (1-z)*n + z*h
    }

    // ---- layer 2 cell: gi = W_ih2 @ h1_new + b_ih2 ; gh = W_hh2 @ h2 + b_hh2
    float gi[24];
    #pragma unroll
    for (int g = 0; g < 24; ++g) {
      float a = b_ih2[g];
      #pragma unroll
      for (int j = 0; j < 8; ++j) a = fmaf(w_ih2[g * 8 + j], h1[j], a);
      gi[g] = a;
    }
    #pragma unroll
    for (int g = 0; g < 24; ++g) {
      float a = b_hh2[g];
      #pragma unroll
      for (int j = 0; j < 8; ++j) a = fmaf(w_hh2[g * 8 + j], h2[j], a);
      gh[g] = a;
    }
    #pragma unroll
    for (int u = 0; u < 8; ++u) {
      const float r = fsig(gi[u] + gh[u]);
      const float z = fsig(gi[u + 8] + gh[u + 8]);
      const float n = ftanh_(gi[u + 16] + r * gh[u + 16]);
      h2[u] = n + z * (h2[u] - n);
    }
  }

  const long b = (long)blockIdx.x * 256 + threadIdx.x;
  float4* o = (float4*)(out + b * 8);
  o[0] = make_float4(h2[0], h2[1], h2[2], h2[3]);
  o[1] = make_float4(h2[4], h2[5], h2[6], h2[7]);
}

extern "C" void kernel_launch(void* const* d_in, const int* in_sizes, int n_in,
                              void* d_out, int out_size, void* d_ws, size_t ws_size,
                              hipStream_t stream) {
  const int*   inputs = (const int*)d_in[0];
  const float* emb    = (const float*)d_in[1];
  const float* w_ih1  = (const float*)d_in[2];
  const float* w_hh1  = (const float*)d_in[3];
  const float* b_ih1  = (const float*)d_in[4];
  const float* b_hh1  = (const float*)d_in[5];
  const float* w_ih2  = (const float*)d_in[6];
  const float* w_hh2  = (const float*)d_in[7];
  const float* b_ih2  = (const float*)d_in[8];
  const float* b_hh2  = (const float*)d_in[9];
  float* out = (float*)d_out;

  const int B = in_sizes[0] / 24;   // 131072
  const int grid = B / 256;         // 512 blocks

  hipLaunchKernelGGL(gru2_kernel, dim3(grid), dim3(256), 0, stream,
                     inputs, emb, w_ih1, w_hh1, b_ih1, b_hh1,
                     w_ih2, w_hh2, b_ih2, b_hh2, out);
}

// Round 7
// 167.057 us; speedup vs baseline: 2.0456x; 2.0456x over previous
//
#include <hip/hip_runtime.h>

// 2-layer GRU, B=131072, T=24, H=8. One thread per sequence.
// vs round-2 baseline (280 us, VALUBusy 88%):
//  - weights pre-packed to f16 pairs (pre-pass kernel into d_ws), main kernel
//    uses v_dot2_f32_f16: halves matvec instr count AND s_load dword traffic.
//  - gh2 (depends only on h2 from prev step) computed right after gh1 so the
//    two independent matvecs interleave.
// Fix vs round-5 compile error: h2f element type must be __fp16 (what
// __builtin_amdgcn_cvt_pkrtz returns / __builtin_amdgcn_fdot2 takes),
// not _Float16.

typedef __fp16 h2f __attribute__((ext_vector_type(2)));

__device__ __forceinline__ h2f pack2(float a, float b) {
  return __builtin_amdgcn_cvt_pkrtz(a, b);
}

__device__ __forceinline__ float dot2(h2f w, h2f x, float acc) {
#if __has_builtin(__builtin_amdgcn_fdot2)
  return __builtin_amdgcn_fdot2(w, x, acc, false);
#else
  return fmaf((float)w[0], (float)x[0], fmaf((float)w[1], (float)x[1], acc));
#endif
}

__device__ __forceinline__ float fsig(float x) {
  float e = __builtin_amdgcn_exp2f(-1.44269504089f * x);
  return __builtin_amdgcn_rcpf(1.0f + e);
}
__device__ __forceinline__ float ftanh_(float x) {
  float e = __builtin_amdgcn_exp2f(2.88539008178f * x);
  return 1.0f - 2.0f * __builtin_amdgcn_rcpf(1.0f + e);
}

// Pack w_hh1 / w_ih2 / w_hh2 (each 24x8 f32) into f16 pairs: 96 dwords each.
__global__ void pack_w(const float* __restrict__ w_hh1,
                       const float* __restrict__ w_ih2,
                       const float* __restrict__ w_hh2,
                       h2f* __restrict__ ws) {
  const int i = threadIdx.x;
  if (i < 96) {
    ws[i]       = pack2(w_hh1[2 * i], w_hh1[2 * i + 1]);
    ws[96 + i]  = pack2(w_ih2[2 * i], w_ih2[2 * i + 1]);
    ws[192 + i] = pack2(w_hh2[2 * i], w_hh2[2 * i + 1]);
  }
}

__global__ __launch_bounds__(256, 2) void gru2_kernel(
    const int* __restrict__ inputs,
    const float* __restrict__ emb,
    const float* __restrict__ w_ih1,
    const float* __restrict__ b_ih1, const float* __restrict__ b_hh1,
    const float* __restrict__ b_ih2, const float* __restrict__ b_hh2,
    const h2f* __restrict__ wpk,          // [0:96) whh1, [96:192) wih2, [192:288) whh2
    float* __restrict__ out)
{
  // stride-25 padding: bank = (25*tok + g) % 32 -> 27 distinct tokens hit 27
  // distinct banks (25 coprime 32) -> conflict-free; equal tokens broadcast.
  __shared__ float G1[27 * 25];
  __shared__ int   TK[256 * 25];

  // --- precompute layer-1 input gates for all 27 vocab entries (f32) ---
  for (int idx = threadIdx.x; idx < 27 * 24; idx += 256) {
    const int v = idx / 24, g = idx % 24;
    float a = b_ih1[g];
    #pragma unroll
    for (int j = 0; j < 8; ++j) a = fmaf(w_ih1[g * 8 + j], emb[v * 8 + j], a);
    G1[v * 25 + g] = a;
  }

  // --- stage this block's 256x24 tokens, coalesced ---
  const long base = (long)blockIdx.x * (256 * 24);
  #pragma unroll
  for (int k = 0; k < 24; ++k) {
    const int i = threadIdx.x + k * 256;
    TK[(i / 24) * 25 + (i % 24)] = inputs[base + i];
  }
  __syncthreads();

  const h2f* __restrict__ whh1 = wpk;
  const h2f* __restrict__ wih2 = wpk + 96;
  const h2f* __restrict__ whh2 = wpk + 192;

  float h1[8], h2[8];
  h2f hp1[4], hp2[4];
  #pragma unroll
  for (int u = 0; u < 8; ++u) { h1[u] = 0.f; h2[u] = 0.f; }
  #pragma unroll
  for (int p = 0; p < 4; ++p) { hp1[p] = pack2(0.f, 0.f); hp2[p] = pack2(0.f, 0.f); }

  const int trow = threadIdx.x * 25;

  for (int t = 0; t < 24; ++t) {
    const int tok = TK[trow + t];
    const float* gi1 = &G1[tok * 25];

    // ---- layer-1 recurrent gates (needs h1 from prev step) ----
    float gha[24];
    #pragma unroll
    for (int g = 0; g < 24; ++g) {
      float a = b_hh1[g];
      #pragma unroll
      for (int p = 0; p < 4; ++p) a = dot2(whh1[g * 4 + p], hp1[p], a);
      gha[g] = a;
    }
    // ---- layer-2 recurrent gates (needs only h2 from prev step: independent,
    //      interleaves with gha above) ----
    float ghb[24];
    #pragma unroll
    for (int g = 0; g < 24; ++g) {
      float a = b_hh2[g];
      #pragma unroll
      for (int p = 0; p < 4; ++p) a = dot2(whh2[g * 4 + p], hp2[p], a);
      ghb[g] = a;
    }

    // ---- layer-1 cell ----
    #pragma unroll
    for (int u = 0; u < 8; ++u) {
      const float r = fsig(gi1[u] + gha[u]);
      const float z = fsig(gi1[u + 8] + gha[u + 8]);
      const float n = ftanh_(gi1[u + 16] + r * gha[u + 16]);
      h1[u] = n + z * (h1[u] - n);
    }
    #pragma unroll
    for (int p = 0; p < 4; ++p) hp1[p] = pack2(h1[2 * p], h1[2 * p + 1]);

    // ---- layer-2 input gates from fresh h1 ----
    float gic[24];
    #pragma unroll
    for (int g = 0; g < 24; ++g) {
      float a = b_ih2[g];
      #pragma unroll
      for (int p = 0; p < 4; ++p) a = dot2(wih2[g * 4 + p], hp1[p], a);
      gic[g] = a;
    }

    // ---- layer-2 cell ----
    #pragma unroll
    for (int u = 0; u < 8; ++u) {
      const float r = fsig(gic[u] + ghb[u]);
      const float z = fsig(gic[u + 8] + ghb[u + 8]);
      const float n = ftanh_(gic[u + 16] + r * ghb[u + 16]);
      h2[u] = n + z * (h2[u] - n);
    }
    #pragma unroll
    for (int p = 0; p < 4; ++p) hp2[p] = pack2(h2[2 * p], h2[2 * p + 1]);
  }

  const long b = (long)blockIdx.x * 256 + threadIdx.x;
  float4* o = (float4*)(out + b * 8);
  o[0] = make_float4(h2[0], h2[1], h2[2], h2[3]);
  o[1] = make_float4(h2[4], h2[5], h2[6], h2[7]);
}

extern "C" void kernel_launch(void* const* d_in, const int* in_sizes, int n_in,
                              void* d_out, int out_size, void* d_ws, size_t ws_size,
                              hipStream_t stream) {
  const int*   inputs = (const int*)d_in[0];
  const float* emb    = (const float*)d_in[1];
  const float* w_ih1  = (const float*)d_in[2];
  const float* w_hh1  = (const float*)d_in[3];
  const float* b_ih1  = (const float*)d_in[4];
  const float* b_hh1  = (const float*)d_in[5];
  const float* w_ih2  = (const float*)d_in[6];
  const float* w_hh2  = (const float*)d_in[7];
  const float* b_ih2  = (const float*)d_in[8];
  const float* b_hh2  = (const float*)d_in[9];
  float* out = (float*)d_out;

  h2f* wpk = (h2f*)d_ws;   // 288 dwords

  hipLaunchKernelGGL(pack_w, dim3(1), dim3(128), 0, stream,
                     w_hh1, w_ih2, w_hh2, wpk);

  const int B = in_sizes[0] / 24;   // 131072
  const int grid = B / 256;         // 512 blocks

  hipLaunchKernelGGL(gru2_kernel, dim3(grid), dim3(256), 0, stream,
                     inputs, emb, w_ih1, b_ih1, b_hh1, b_ih2, b_hh2, wpk, out);
}

// Round 8
// 111.718 us; speedup vs baseline: 3.0589x; 1.4953x over previous
//
#include <hip/hip_runtime.h>

// 2-layer GRU, B=131072, T=24, H=8.
// Round-8: MFMA reformulation. 32 seqs per wave; v_mfma_f32_32x32x16_f16
// computes all 24 gate pre-activations for 32 seqs in one instruction
// (A = weights [gate][k], K=8 padded to 16; B = h [k][seq]).
// - Lanes>=32 hold K=8..15 of A = zeros => B-frag content there is don't-care.
// - Layer-1 input gates: 27-token LDS table (stride 26 dwords, <=2-way bank
//   conflicts) loaded as the MFMA C operand (6x ds_read_b64 per step).
// - All preactivations pre-scaled by -log2e (r,z) / +2log2e (n) at weight
//   load => sigmoid = rcp(1+exp2(x)), tanh = 1-2*rcp(1+exp2(x)), no muls.
// - Layer-2: dh = W_hh2*h2 + biasfrag; dg = W_ih2*h1 + dh (chained C).
// - h halves exchanged lane<->lane^32 via ds_bpermute (2 dwords).
// 4096 waves (vs 2048) => 4 waves/SIMD; VALU stream per step ~= 140 ops
// vs ~600 before.

typedef __fp16 h2f   __attribute__((ext_vector_type(2)));
typedef __fp16 half8 __attribute__((ext_vector_type(8)));
typedef float  f32x16 __attribute__((ext_vector_type(16)));

#define LOG2E 1.44269504088896f

__device__ __forceinline__ h2f pk2(float a, float b) {
  return __builtin_amdgcn_cvt_pkrtz(a, b);
}

union H8U { half8 h; unsigned u[4]; h2f p[4]; };

__global__ __launch_bounds__(256, 4) void gru2_mfma(
    const int* __restrict__ inputs,
    const float* __restrict__ emb,
    const float* __restrict__ w_ih1, const float* __restrict__ w_hh1,
    const float* __restrict__ b_ih1, const float* __restrict__ b_hh1,
    const float* __restrict__ w_ih2, const float* __restrict__ w_hh2,
    const float* __restrict__ b_ih2, const float* __restrict__ b_hh2,
    float* __restrict__ out)
{
  __shared__ float G1f[27 * 26];   // [token][gate], stride 26 dwords
  __shared__ int   TK[128 * 25];   // block's 128 seqs x 24 tokens, stride 25

  const int tid   = threadIdx.x;
  const int lane  = tid & 63;
  const int wid   = tid >> 6;      // wave in block (0..3)
  const int half_ = lane >> 5;     // 0: rows {0-3,8-11,16-19}; 1: {4-7,...}
  const int col   = lane & 31;     // seq-in-wave / gate-row for A

  // ---- G1 table: scaled input-side gates for all 27 tokens ----
  // r,z rows (g<16): -log2e*(b_ih1 + b_hh1 + W_ih1*emb)
  // n   rows (g>=16): 2log2e*(b_ih1 + W_ih1*emb)   (b_hh1_n goes in C regs 8-11)
  for (int idx = tid; idx < 27 * 24; idx += 256) {
    const int tok = idx / 24, g = idx - tok * 24;
    const float s = (g < 16) ? -LOG2E : 2.f * LOG2E;
    float a = b_ih1[g] + ((g < 16) ? b_hh1[g] : 0.f);
    if (tok != 0) {  // padding_idx=0 -> zero embedding row
      #pragma unroll
      for (int j = 0; j < 8; ++j) a = fmaf(w_ih1[g * 8 + j], emb[tok * 8 + j], a);
    }
    G1f[tok * 26 + g] = s * a;
  }

  // ---- stage tokens (coalesced), then pack 24x5b into 4 dwords/lane ----
  const long gbase = (long)blockIdx.x * (128 * 24);
  #pragma unroll
  for (int k = 0; k < 12; ++k) {
    const int i = tid + k * 256;
    TK[(i / 24) * 25 + (i % 24)] = inputs[gbase + i];
  }
  __syncthreads();

  const int sl = wid * 32 + col;   // local seq (both lane halves same seq)
  unsigned pkw[4] = {0u, 0u, 0u, 0u};
  #pragma unroll
  for (int t = 0; t < 24; ++t)
    pkw[t / 6] |= ((unsigned)TK[sl * 25 + t]) << (5 * (t % 6));
  const unsigned pk0 = pkw[0], pk1 = pkw[1], pk2_ = pkw[2], pk3 = pkw[3];

  // ---- weight A-frags: lane<32 holds row=col of W (8 f16, k=0..7), scaled;
  //      lane>=32 holds k=8..15 = zeros; rows>=24 zero. ----
  auto loadW = [&](const float* w) -> half8 {
    H8U u;
    u.u[0] = u.u[1] = u.u[2] = u.u[3] = 0u;
    if (half_ == 0 && col < 24) {
      const float s = (col < 16) ? -LOG2E : 2.f * LOG2E;
      const float4* p = (const float4*)(w + col * 8);
      const float4 x = p[0], y = p[1];
      u.p[0] = pk2(x.x * s, x.y * s);
      u.p[1] = pk2(x.z * s, x.w * s);
      u.p[2] = pk2(y.x * s, y.y * s);
      u.p[3] = pk2(y.z * s, y.w * s);
    }
    return u.h;
  };
  const half8 wa1  = loadW(w_hh1);
  const half8 wa2i = loadW(w_ih2);
  const half8 wa2h = loadW(w_hh2);

  // ---- layer-2 bias C-frag (for dh): rows<16: -log2e*(b_ih2+b_hh2);
  //      rows 16-23: 2log2e*b_hh2; pad 0 ----
  f32x16 c2;
  #pragma unroll
  for (int r = 0; r < 16; ++r) {
    const int m = (r & 3) + 8 * (r >> 2) + 4 * half_;
    float v;
    if (m < 16)      v = -LOG2E * (b_ih2[m] + b_hh2[m]);
    else if (m < 24) v = 2.f * LOG2E * b_hh2[m];
    else             v = 0.f;
    c2[r] = v;
  }
  float bn1[4], bi2n[4];
  #pragma unroll
  for (int i = 0; i < 4; ++i) {
    bn1[i]  = 2.f * LOG2E * b_hh1[16 + 4 * half_ + i];
    bi2n[i] = 2.f * LOG2E * b_ih2[16 + 4 * half_ + i];
  }

  float h1v[4] = {0.f, 0.f, 0.f, 0.f}, h2v[4] = {0.f, 0.f, 0.f, 0.f};
  H8U f1, f2;
  f1.u[0] = f1.u[1] = f1.u[2] = f1.u[3] = 0u;
  f2 = f1;

  const float* g1base = G1f + half_ * 4;
  const int pidx = (lane ^ 32) << 2;   // ds_bpermute byte index of partner lane

  for (int g = 0; g < 4; ++g) {
    unsigned pw = pk0;
    if (g == 1) pw = pk1;
    if (g == 2) pw = pk2_;
    if (g == 3) pw = pk3;

    #pragma unroll
    for (int j = 0; j < 6; ++j) {
      const unsigned tok = (pw >> (5 * j)) & 31u;
      const float* gp = g1base + tok * 26;
      const float2 a01 = *(const float2*)(gp + 0);
      const float2 a23 = *(const float2*)(gp + 2);
      const float2 z01 = *(const float2*)(gp + 8);
      const float2 z23 = *(const float2*)(gp + 10);
      const float2 n01 = *(const float2*)(gp + 16);
      const float2 n23 = *(const float2*)(gp + 18);

      f32x16 c1;
      c1[0] = a01.x; c1[1] = a01.y; c1[2] = a23.x; c1[3] = a23.y;
      c1[4] = z01.x; c1[5] = z01.y; c1[6] = z23.x; c1[7] = z23.y;
      c1[8] = bn1[0]; c1[9] = bn1[1]; c1[10] = bn1[2]; c1[11] = bn1[3];
      c1[12] = 0.f; c1[13] = 0.f; c1[14] = 0.f; c1[15] = 0.f;

      // d1 rows: r(0-3/4-7), z(8-11/12-15), n(16-19/20-23)
      const f32x16 d1 = __builtin_amdgcn_mfma_f32_32x32x16_f16(wa1, f1.h, c1, 0, 0, 0);

      const float gin1[4] = {n01.x, n01.y, n23.x, n23.y};
      #pragma unroll
      for (int i = 0; i < 4; ++i) {
        const float r = __builtin_amdgcn_rcpf(1.f + __builtin_amdgcn_exp2f(d1[i]));
        const float z = __builtin_amdgcn_rcpf(1.f + __builtin_amdgcn_exp2f(d1[4 + i]));
        const float na = fmaf(r, d1[8 + i], gin1[i]);
        const float n = fmaf(-2.f, __builtin_amdgcn_rcpf(1.f + __builtin_amdgcn_exp2f(na)), 1.f);
        h1v[i] = n + z * (h1v[i] - n);
      }
      {
        const unsigned a = __builtin_bit_cast(unsigned, pk2(h1v[0], h1v[1]));
        const unsigned b = __builtin_bit_cast(unsigned, pk2(h1v[2], h1v[3]));
        f1.u[0] = a; f1.u[1] = b;
        f1.u[2] = (unsigned)__builtin_amdgcn_ds_bpermute(pidx, (int)a);
        f1.u[3] = (unsigned)__builtin_amdgcn_ds_bpermute(pidx, (int)b);
      }

      // layer 2: dh = W_hh2*h2 + bias; dg = W_ih2*h1_new + dh (chained C)
      const f32x16 dh = __builtin_amdgcn_mfma_f32_32x32x16_f16(wa2h, f2.h, c2, 0, 0, 0);
      const f32x16 dg = __builtin_amdgcn_mfma_f32_32x32x16_f16(wa2i, f1.h, dh, 0, 0, 0);

      #pragma unroll
      for (int i = 0; i < 4; ++i) {
        const float r = __builtin_amdgcn_rcpf(1.f + __builtin_amdgcn_exp2f(dg[i]));
        const float z = __builtin_amdgcn_rcpf(1.f + __builtin_amdgcn_exp2f(dg[4 + i]));
        const float gin = dg[8 + i] - dh[8 + i] + bi2n[i];   // gic_n + b_ih2n
        const float na = fmaf(r, dh[8 + i], gin);
        const float n = fmaf(-2.f, __builtin_amdgcn_rcpf(1.f + __builtin_amdgcn_exp2f(na)), 1.f);
        h2v[i] = n + z * (h2v[i] - n);
      }
      {
        const unsigned a = __builtin_bit_cast(unsigned, pk2(h2v[0], h2v[1]));
        const unsigned b = __builtin_bit_cast(unsigned, pk2(h2v[2], h2v[3]));
        f2.u[0] = a; f2.u[1] = b;
        f2.u[2] = (unsigned)__builtin_amdgcn_ds_bpermute(pidx, (int)a);
        f2.u[3] = (unsigned)__builtin_amdgcn_ds_bpermute(pidx, (int)b);
      }
    }
  }

  // lane<32 holds h2[0..3] of seq, lane>=32 holds h2[4..7]
  const long seq = (long)blockIdx.x * 128 + sl;
  *(float4*)(out + seq * 8 + 4 * half_) =
      make_float4(h2v[0], h2v[1], h2v[2], h2v[3]);
}

extern "C" void kernel_launch(void* const* d_in, const int* in_sizes, int n_in,
                              void* d_out, int out_size, void* d_ws, size_t ws_size,
                              hipStream_t stream) {
  const int*   inputs = (const int*)d_in[0];
  const float* emb    = (const float*)d_in[1];
  const float* w_ih1  = (const float*)d_in[2];
  const float* w_hh1  = (const float*)d_in[3];
  const float* b_ih1  = (const float*)d_in[4];
  const float* b_hh1  = (const float*)d_in[5];
  const float* w_ih2  = (const float*)d_in[6];
  const float* w_hh2  = (const float*)d_in[7];
  const float* b_ih2  = (const float*)d_in[8];
  const float* b_hh2  = (const float*)d_in[9];
  float* out = (float*)d_out;

  const int B = in_sizes[0] / 24;        // 131072
  const int grid = B / 128;              // 1024 blocks (128 seqs per block)

  hipLaunchKernelGGL(gru2_mfma, dim3(grid), dim3(256), 0, stream,
                     inputs, emb, w_ih1, w_hh1, b_ih1, b_hh1,
                     w_ih2, w_hh2, b_ih2, b_hh2, out);
}